// Round 2
// baseline (31.967 us; speedup 1.0000x reference)
//
#include <hip/hip_runtime.h>
#include <cstdint>
#include <cstddef>

#define B_ 32
#define V_ 8
#define S_ 4096
#define E_ 64
#define WIN_ 16
#define STEP_ 4
#define T_ 1020   // len(arange(0, S-WIN, STEP)) = 4080/4

typedef __bf16 bf16_t;
typedef bf16_t bf16x8 __attribute__((ext_vector_type(8)));
typedef float f32x4 __attribute__((ext_vector_type(4)));

// ---------------- stage 1: e[b][d][s] = floor(sum_v x[b][v][s]*W1[v][d] + b1[d]) ----------------
// e stored bf16 (values are small exact integers), layout [B][E][S] so that
// 8 consecutive s (= 8 consecutive k of the MFMA A fragment) are contiguous.
__global__ __launch_bounds__(256) void stage1_kernel(const float* __restrict__ x,
                                                     const float* __restrict__ W1,
                                                     const float* __restrict__ b1,
                                                     bf16_t* __restrict__ eb) {
  __shared__ float w1s[V_ * E_];
  __shared__ float b1s[E_];
  __shared__ bf16_t tile[E_ * 256];   // [d][s_local]
  const int tid = threadIdx.x;
  const int b = blockIdx.y;
  const int s0 = blockIdx.x * 256;
  for (int i = tid; i < V_ * E_; i += 256) w1s[i] = W1[i];   // FIX: 512 > 256 threads
  if (tid < E_) b1s[tid] = b1[tid];
  __syncthreads();
  const int s = s0 + tid;
  float xv[V_];
#pragma unroll
  for (int v = 0; v < V_; ++v) xv[v] = x[((size_t)(b * V_ + v) << 12) + s];
  for (int d = 0; d < E_; ++d) {
    float acc = b1s[d];
#pragma unroll
    for (int v = 0; v < V_; ++v) acc += xv[v] * w1s[v * E_ + d];
    tile[d * 256 + tid] = (bf16_t)floorf(acc);
  }
  __syncthreads();
  // coalesced write-out: 64 rows x 256 bf16, 16B per thread-iter
  for (int i = tid; i < E_ * 32; i += 256) {
    const int row = i >> 5, seg = i & 31;
    *reinterpret_cast<bf16x8*>(eb + (((size_t)(b * E_ + row)) << 12) + s0 + seg * 8) =
        *reinterpret_cast<const bf16x8*>(tile + row * 256 + seg * 8);
  }
}

// ---------------- prep: W2T[n][f] = (bf16) W2[f][n] ----------------
__global__ __launch_bounds__(256) void prep_w2_kernel(const float* __restrict__ W2,
                                                      bf16_t* __restrict__ w2t) {
  const int i = blockIdx.x * 256 + threadIdx.x;
  if (i < WIN_ * E_ * E_) {   // 65536
    const int n = i >> 10, f = i & 1023;
    w2t[i] = (bf16_t)W2[f * E_ + n];
  }
}

// ---------------- stage 2: tokens[b][t][n] = floor(sum_f flat[b,t,f]*W2[f,n] + b2[n]) ----------------
// flat[b,t,f] = e[b, f>>4, 4t + (f&15)].  MFMA 16x16x32 bf16.
// Block: 256 thr = 4 waves; block tile = 64 tokens x 64 outs; K = 1024 in 4 LDS chunks of 256.
#define CHUNK 256
#define LDSLD (CHUNK + 8)   // +16B pad per row -> <=2-way bank aliasing on ds_read_b128
__global__ __launch_bounds__(256) void stage2_kernel(const bf16_t* __restrict__ eb,
                                                     const bf16_t* __restrict__ w2t,
                                                     const float* __restrict__ b2,
                                                     float* __restrict__ out) {
  __shared__ bf16_t ldsb[E_ * LDSLD];
  const int tid = threadIdx.x;
  const int lane = tid & 63;
  const int wid = tid >> 6;
  const int b = blockIdx.y;
  const int t0 = blockIdx.x * 64;
  const int l15 = lane & 15;
  const int g = lane >> 4;
  // A fragment: row = lane&15 (token), k = g*8 + j ; f = kk*32 + k -> d = 2kk + (g>>1), w = (g&1)*8 + j
  const int t = t0 + wid * 16 + l15;
  const int te = (t < T_) ? t : (T_ - 1);          // clamp tail (stores are masked)
  const int woff = (g & 1) * 8;
  const size_t ebase = ((size_t)b << 18);          // b * E_ * S_
  f32x4 acc[4] = {};                               // 4 n-tiles of 16
  for (int c = 0; c < 4; ++c) {
    __syncthreads();
    // stage W2T chunk c: rows n=0..63, f_local=0..255 (16B per thread-iter)
    for (int i = tid; i < E_ * 32; i += 256) {
      const int row = i >> 5, seg = i & 31;
      *reinterpret_cast<bf16x8*>(&ldsb[row * LDSLD + seg * 8]) =
          *reinterpret_cast<const bf16x8*>(&w2t[row * 1024 + c * CHUNK + seg * 8]);
    }
    __syncthreads();
    for (int k8 = 0; k8 < 8; ++k8) {
      const int kk = c * 8 + k8;
      const int d = 2 * kk + (g >> 1);
      // 16B of A = e[b, d, 4*te+woff .. +8): only 8B-aligned -> two 8B loads
      const uint64_t* ap = reinterpret_cast<const uint64_t*>(
          eb + ebase + ((size_t)d << 12) + 4 * te + woff);
      union { uint64_t q[2]; bf16x8 v; } au;
      au.q[0] = ap[0];
      au.q[1] = ap[1];
      const int fb = k8 * 32 + g * 8;              // f_local for B fragment
#pragma unroll
      for (int nt = 0; nt < 4; ++nt) {
        const bf16x8 bfrag = *reinterpret_cast<const bf16x8*>(
            &ldsb[(nt * 16 + l15) * LDSLD + fb]);
        acc[nt] = __builtin_amdgcn_mfma_f32_16x16x32_bf16(au.v, bfrag, acc[nt], 0, 0, 0);
      }
    }
  }
  // epilogue: C/D layout col = lane&15 (n), row = g*4 + r (token)
#pragma unroll
  for (int nt = 0; nt < 4; ++nt) {
    const int n = nt * 16 + l15;
    const float bb = b2[n];
#pragma unroll
    for (int r = 0; r < 4; ++r) {
      const int tt = t0 + wid * 16 + g * 4 + r;
      if (tt < T_) out[((size_t)(b * T_ + tt)) * E_ + n] = floorf(acc[nt][r] + bb);
    }
  }
}

extern "C" void kernel_launch(void* const* d_in, const int* in_sizes, int n_in,
                              void* d_out, int out_size, void* d_ws, size_t ws_size,
                              hipStream_t stream) {
  const float* x  = (const float*)d_in[0];
  const float* W1 = (const float*)d_in[1];
  const float* b1 = (const float*)d_in[2];
  const float* W2 = (const float*)d_in[3];
  const float* b2 = (const float*)d_in[4];
  float* out = (float*)d_out;

  bf16_t* eb  = (bf16_t*)d_ws;                        // [B][E][S] bf16 = 16 MiB
  bf16_t* w2t = eb + (size_t)B_ * E_ * S_;            // [E][WIN*E] bf16 = 128 KiB

  hipLaunchKernelGGL(stage1_kernel, dim3(S_ / 256, B_), dim3(256), 0, stream, x, W1, b1, eb);
  hipLaunchKernelGGL(prep_w2_kernel, dim3(WIN_ * E_ * E_ / 256), dim3(256), 0, stream, W2, w2t);
  hipLaunchKernelGGL(stage2_kernel, dim3((T_ + 63) / 64, B_), dim3(256), 0, stream, eb, w2t, b2, out);
}